// Round 6
// baseline (329.497 us; speedup 1.0000x reference)
//
#include <hip/hip_runtime.h>
#include <cstdint>
#include <cstddef>

#define MDIM 4096   // batch
#define NDIM 4096   // out features
#define KDIM 4096   // in features

typedef _Float16 half8   __attribute__((ext_vector_type(8)));
typedef float    floatx4 __attribute__((ext_vector_type(4)));

// Hamilton product tables: out_comp = sum_c sign[comp][c] * (x_c @ W_{comp^c}^T)
__device__ __constant__ int   d_qtab[16] = {0,1,2,3,  1,0,3,2,  2,3,0,1,  3,2,1,0};
__device__ __constant__ float d_stab[16] = {1.f,-1.f,-1.f,-1.f,
                                            1.f, 1.f, 1.f,-1.f,
                                            1.f,-1.f, 1.f, 1.f,
                                            1.f, 1.f,-1.f, 1.f};

// ---------------- fused pre-pass: cast x -> fp16, cast W -> fp16 ----------------
__global__ void prepass_kernel(const float* __restrict__ x,
                               const float* __restrict__ W0, const float* __restrict__ W1,
                               const float* __restrict__ W2, const float* __restrict__ W3,
                               _Float16* __restrict__ xh, _Float16* __restrict__ Wh) {
    int b = blockIdx.x;
    if (b < 8192) {
        int idx = b * 256 + threadIdx.x;               // 0 .. 2M-1
        const float4* src = (const float4*)x + (size_t)idx * 2;
        float4 a = src[0], v = src[1];
        half8 h = {(_Float16)a.x, (_Float16)a.y, (_Float16)a.z, (_Float16)a.w,
                   (_Float16)v.x, (_Float16)v.y, (_Float16)v.z, (_Float16)v.w};
        ((half8*)xh)[idx] = h;
    } else {
        int idx = (b - 8192) * 256 + threadIdx.x;      // 0 .. 512K-1
        int e = idx << 3;                               // 0 .. 4M-1
        int m = e >> 20;
        int off = e & ((1 << 20) - 1);
        const float* Ws[4] = {W0, W1, W2, W3};
        const float* src = Ws[m] + off;
        float4 a = *(const float4*)src;
        float4 v = *(const float4*)(src + 4);
        half8 h = {(_Float16)a.x, (_Float16)a.y, (_Float16)a.z, (_Float16)a.w,
                   (_Float16)v.x, (_Float16)v.y, (_Float16)v.z, (_Float16)v.w};
        *(half8*)(Wh + ((size_t)m << 20) + off) = h;
    }
}

// --- MFMA GEMM: 256x256 tile, BK=64, 8 waves; A via LDS, B direct from L2 ---
// R6 = R5 with the LDB addressing bug fixed: the K-offset into a W row is
// segment-LOCAL, ((TT)&15)*64, not TT*64 (W rows are 1024 halves wide; R5
// walked into adjacent rows for tt>=16 -> absmax 8.37).
// Structure (from R5):
//  1) B fragments are loaded global->VGPR (W is 8MB, L2-resident; 16 rows x
//     64B contiguous segments per load), prefetched 1 phase ahead into the
//     bf0/bf1 ping-pong. Deletes B's ds_reads (64KB/tile) and B DMA
//     (32KB/tile): LDS demand 256->160KB/tile, LDS footprint 128->64KB.
//  2) Sign handling: no per-fragment negation. The accumulator is flipped at
//     the negated-segment boundaries (<=2 x 128 v_xor per KERNEL) and the
//     residue folds into the epilogue sign esign = (comp<=1 ? -1 : +1).
//     acc invariant: acc_stored = sigma(seg)*acc_true inside negseg.
//  3) vmcnt ledger (simulated from prologue; steady state): at ph4's
//     WAITVM(6) queue = [Ag0(t+2)x2, bf0(t+1)x4]. Ag0(t+1) retires at ph1's
//     compiler bf0-wait (vmcnt 6), published by ph1-end BAR, read at ph4.
//     Ag1(t+1) retires at ph4 WAITVM(6), published by ph4-end BAR, read at
//     ph2(t+1). All LDS WAR windows have >=1 BAR between read-retire (lgkm
//     wait before consuming MFMA) and the overwriting DMA.
// Phases (cur=tt&1, nxt=cur^1):
//  ph1: rd afQ(g0,sl1); LDB bf1(tt,kh1); STA Ag1(t+1)->nxt; MFMA(afP,bf0)
//  ph2: rd afP(g1,sl0);                                     MFMA(afQ,bf1)
//  ph3: rd afQ(g1,sl1);                  STA Ag0(t+2)->cur; MFMA(afP,bf0)
//  ph4: rd afP(nxt g0,sl0); LDB bf0(t+1,kh0);               MFMA(afQ,bf1); VM(6)
// LDS geometry: rows of 64 halves (128B), slot = chunk ^ (row&7) (0 conflicts
// measured R0/R1/R3/R4). Tail: t1/t2 clamped to 63 (dead restages, ledger
// shape invariant).

__device__ __forceinline__ void gload_lds16(const _Float16* g, _Float16* l) {
    __builtin_amdgcn_global_load_lds(
        (const __attribute__((address_space(1))) unsigned int*)g,
        (__attribute__((address_space(3))) unsigned int*)l,
        16, 0, 0);
}

#define BAR __builtin_amdgcn_s_barrier()
#define SCHEDB __builtin_amdgcn_sched_barrier(0)
#define WAITVM(N) asm volatile("s_waitcnt vmcnt(" #N ")" ::: "memory")

// stage A quadrant-half g of K-tile tt into buffer buf (2 x 64 rows)
#define STA(g, tt, buf) { \
    const _Float16* _s = Abase + (size_t)((g) * 64) * KDIM + (tt) * 64; \
    _Float16* _d = AsSt + (buf) * 16384 + (g) * 8192; \
    gload_lds16(_s, _d); \
    gload_lds16(_s + (size_t)128 * KDIM, _d + 4096); }

// B fragments straight from global (L2-resident W).
// Row-local k = ((TT)&15)*64 + KH*32 + qf*8  [FIXED: was TT*64 in R5]
#define LDB(BQ, TT, KH) { \
    const _Float16* _bp = Wh + ((size_t)(comp ^ ((TT) >> 4)) << 20) \
                             + ((TT) & 15) * 64 + (KH) * 32; \
    BQ[0] = *(const half8*)(_bp + boff0); \
    BQ[1] = *(const half8*)(_bp + boff1); \
    BQ[2] = *(const half8*)(_bp + boff2); \
    BQ[3] = *(const half8*)(_bp + boff3); }

#define RDA(AF, BASE, g, SL) { \
    const _Float16* _p = (BASE) + (g) * 8192 + arow + (SL); \
    AF[0] = *(const half8*)(_p); \
    AF[1] = *(const half8*)(_p + 1024); \
    AF[2] = *(const half8*)(_p + 2048); \
    AF[3] = *(const half8*)(_p + 3072); }

#define MFMA16(IB, AF, BQ) \
    _Pragma("unroll") \
    for (int _i = 0; _i < 4; _i++) \
      _Pragma("unroll") \
      for (int _j = 0; _j < 4; _j++) \
        acc[(IB) + _i][_j] = __builtin_amdgcn_mfma_f32_16x16x32_f16( \
            AF[_i], BQ[_j], acc[(IB) + _i][_j], 0, 0, 0);

__global__ __launch_bounds__(512, 2) void gemm_kernel(
        const _Float16* __restrict__ A,      // [4096,4096] fp16
        const _Float16* __restrict__ Wh,     // [4][1024][1024] fp16
        const float* __restrict__ b0, const float* __restrict__ b1,
        const float* __restrict__ b2, const float* __restrict__ b3,
        float* __restrict__ C) {
    __shared__ _Float16 lds[32768];          // 64 KiB: A only, [buf][g][8192]
    _Float16* As = lds;

    const int tid  = threadIdx.x;
    const int lane = tid & 63;
    const int wave = tid >> 6;               // 0..7
    const int wmh  = wave >> 2;              // M-half of 256-row tile (0/1)
    const int wn   = (wave & 3) * 64;        // N offset within 256-col tile

    // bijective XCD swizzle (nwg=256): each XCD gets 2 full bm-rows -> A-panel
    // L2 locality. (B working set is all 4 W's = 8MB for every block anyway.)
    const int wg = ((blockIdx.x & 7) << 5) | (blockIdx.x >> 3);
    const int bm = wg >> 4, bn = wg & 15;
    const int m0 = bm << 8;
    const int n0 = bn << 8;
    const int comp = bn >> 2;                // output quaternion component
    const int n0q  = n0 & 1023;

    // A staging geometry: 8 threads/row, 16B chunks, slot s = chunk s^(row&7)
    const int lrow = tid >> 3;               // 0..63
    const int gch  = (tid & 7) ^ (lrow & 7);
    const _Float16* Abase = A + (size_t)(m0 + lrow) * KDIM + gch * 8;
    _Float16* AsSt = As + tid * 8;

    // fragment geometry (16x16x32): m/n = fr, k = kh*32 + qf*8 + j
    const int fr  = lane & 15;
    const int qf  = lane >> 4;
    const int fsw = fr & 7;
    const int sl0 = ((0 + qf) ^ fsw) * 8;    // kh=0 slot (halves)
    const int sl1 = ((4 + qf) ^ fsw) * 8;    // kh=1 slot
    const int arow = wmh * 4096 + fr * 64;   // within A quadrant region

    // B per-lane offsets (halves): row = n0q + wn + j*16 + fr, + qf*8 in k
    const int brow_g = n0q + wn + fr;
    const int boff0 = (brow_g +  0) * 1024 + qf * 8;
    const int boff1 = (brow_g + 16) * 1024 + qf * 8;
    const int boff2 = (brow_g + 32) * 1024 + qf * 8;
    const int boff3 = (brow_g + 48) * 1024 + qf * 8;

    // sign plan: one negated K-segment per comp (+ global flip folded into
    // esign). negseg: comp0->0, comp1->3, comp2->1, comp3->2.
    const int negseg = (comp == 0) ? 0 : (comp == 1) ? 3 : (comp == 2) ? 1 : 2;
    const int negFlipA = (negseg == 0) ? 16 : negseg * 16;            // entry/exit
    const int negFlipB = (negseg == 0 || negseg == 3) ? -1 : negseg * 16 + 16;
    const float esign = (comp <= 1) ? -1.f : 1.f;

    floatx4 acc[8][4];
#pragma unroll
    for (int i = 0; i < 8; i++)
#pragma unroll
        for (int j = 0; j < 4; j++)
            acc[i][j] = (floatx4){0.f, 0.f, 0.f, 0.f};

    half8 afP[4], afQ[4], bf0[4], bf1[4];

    // ---- prologue: A(0) both halves, Ag0(1); bf0(tile0,kh0) from global.
    STA(0, 0, 0); STA(1, 0, 0);
    STA(0, 1, 1);
    LDB(bf0, 0, 0);
    WAITVM(6);                               // retire Ag0(0)+Ag1(0); 2 DMA + 4 bf left
    BAR;
    RDA(afP, As, 0, sl0);                    // F1(0)

    for (int tt = 0; tt < 64; ++tt) {
        const int cur = tt & 1, nxt = cur ^ 1;
        const _Float16* Acur = As + cur * 16384;
        const _Float16* Anxt = As + nxt * 16384;
        const int t1 = (tt >= 63) ? 63 : tt + 1;
        const int t2 = (tt >= 62) ? 63 : tt + 2;

        // segment-boundary accumulator flip (<=2 per kernel, wave-uniform)
        if (tt == negFlipA || tt == negFlipB) {
#pragma unroll
            for (int i = 0; i < 8; i++)
#pragma unroll
                for (int j = 0; j < 4; j++)
                    acc[i][j] = -acc[i][j];
        }

        // ---- ph1: consume (afP=g0k0, bf0); prefetch afQ=g0k1, bf1(tt,kh1)
        RDA(afQ, Acur, 0, sl1);
        LDB(bf1, tt, 1);
        STA(1, t1, nxt);                     // Ag1(t+1): region's last read was
        SCHEDB;                              //   ph3(t-1), retired >=2 BARs ago
        __builtin_amdgcn_s_setprio(1);
        MFMA16(0, afP, bf0);                 // bf0 auto-wait FIFO-retires Ag0(t+1)
        __builtin_amdgcn_s_setprio(0);
        BAR;

        // ---- ph2: consume (afQ, bf1); prefetch afP=g1k0
        RDA(afP, Acur, 1, sl0);              // Ag1(t): retired ph4(t-1) WAITVM(6)
        SCHEDB;
        __builtin_amdgcn_s_setprio(1);
        MFMA16(0, afQ, bf1);
        __builtin_amdgcn_s_setprio(0);
        BAR;

        // ---- ph3: consume (afP, bf0 reuse); prefetch afQ=g1k1
        RDA(afQ, Acur, 1, sl1);
        STA(0, t2, cur);                     // Ag0(cur) last read ph1 -> freed
        SCHEDB;
        __builtin_amdgcn_s_setprio(1);
        MFMA16(4, afP, bf0);
        __builtin_amdgcn_s_setprio(0);
        BAR;

        // ---- ph4: consume (afQ, bf1 reuse); prefetch F1(t+1): afP from nxt,
        //      bf0(t+1,kh0) from global
        RDA(afP, Anxt, 0, sl0);              // Ag0(t+1): retired by ph1(t) bf0-wait
        LDB(bf0, t1, 0);
        SCHEDB;
        __builtin_amdgcn_s_setprio(1);
        MFMA16(4, afQ, bf1);
        __builtin_amdgcn_s_setprio(0);
        WAITVM(6);                           // = Ag0(t+2)[2] + bf0(t+1)[4]
        BAR;
    }

    WAITVM(0);   // drain tail DMAs before LDS teardown

    // Epilogue: D[row][col], col = lane&15, row = (lane>>4)*4 + r  [m89 layout]
    const int col   = lane & 15;
    const int rquad = (lane >> 4) * 4;
    const int wm    = wmh * 128;
    const float* bsp[4] = {b0, b1, b2, b3};
#pragma unroll
    for (int j = 0; j < 4; j++) {
        const int gn = n0 + wn + j * 16 + col;
        const int o  = gn & 1023;
        float bv = 0.f;
#pragma unroll
        for (int c = 0; c < 4; c++)
            bv += d_stab[comp * 4 + c] * bsp[comp ^ c][o];
#pragma unroll
        for (int i = 0; i < 8; i++) {
            const int gmb = m0 + wm + i * 16 + rquad;
#pragma unroll
            for (int r = 0; r < 4; r++)
                C[(size_t)(gmb + r) * NDIM + gn] = esign * acc[i][j][r] + bv;
        }
    }
}

// ---------------- fp32 fallback (only if ws too small) ----------------
__global__ void fallback_kernel(const float* __restrict__ x,
                                const float* __restrict__ W0, const float* __restrict__ W1,
                                const float* __restrict__ W2, const float* __restrict__ W3,
                                const float* __restrict__ b0, const float* __restrict__ b1,
                                const float* __restrict__ b2, const float* __restrict__ b3,
                                float* __restrict__ out) {
    int idx = blockIdx.x * 256 + threadIdx.x;   // 16M outputs
    int m = idx >> 12, n = idx & 4095;
    int comp = n >> 10, o = n & 1023;
    const float* Ws[4] = {W0, W1, W2, W3};
    const float* bs[4] = {b0, b1, b2, b3};
    float acc = 0.f;
    for (int c = 0; c < 4; c++) {
        int t = comp * 4 + c;
        const float* wr = Ws[d_qtab[t]] + (size_t)o * 1024;
        const float* xr = x + (size_t)m * 4096 + c * 1024;
        float s = d_stab[t];
        float dot = 0.f;
        for (int i = 0; i < 1024; i += 4) {
            float4 wv = *(const float4*)(wr + i);
            float4 xv = *(const float4*)(xr + i);
            dot += wv.x * xv.x + wv.y * xv.y + wv.z * xv.z + wv.w * xv.w;
        }
        acc += s * dot + s * bs[d_qtab[t]][o];
    }
    out[idx] = acc;
}

// ---------------- launch ----------------
extern "C" void kernel_launch(void* const* d_in, const int* in_sizes, int n_in,
                              void* d_out, int out_size, void* d_ws, size_t ws_size,
                              hipStream_t stream) {
    const float* x = (const float*)d_in[0];
    const float* W[4];
    const float* b[4];
    int wi = 0, bi = 0;
    for (int i = 1; i < n_in && i < 9; i++) {
        if (in_sizes[i] > 4096) { if (wi < 4) W[wi++] = (const float*)d_in[i]; }
        else                    { if (bi < 4) b[bi++] = (const float*)d_in[i]; }
    }
    float* out = (float*)d_out;

    const size_t xh_elems = (size_t)MDIM * KDIM;        // 16M fp16 = 32 MB
    const size_t wh_elems = (size_t)4 * 1024 * 1024;    // 4M fp16 = 8 MB
    const size_t needed = (xh_elems + wh_elems) * 2;

    if (ws_size < needed) {
        fallback_kernel<<<(MDIM * NDIM) / 256, 256, 0, stream>>>(
            x, W[0], W[1], W[2], W[3], b[0], b[1], b[2], b[3], out);
        return;
    }

    _Float16* xh = (_Float16*)d_ws;
    _Float16* Wh = xh + xh_elems;

    prepass_kernel<<<8192 + 2048, 256, 0, stream>>>(x, W[0], W[1], W[2], W[3], xh, Wh);
    gemm_kernel<<<(MDIM / 256) * (NDIM / 256), 512, 0, stream>>>(
        xh, Wh, b[0], b[1], b[2], b[3], out);
}

// Round 7
// 268.060 us; speedup vs baseline: 1.2292x; 1.2292x over previous
//
#include <hip/hip_runtime.h>
#include <cstdint>
#include <cstddef>

#define MDIM 4096   // batch
#define NDIM 4096   // out features
#define KDIM 4096   // in features

typedef _Float16 half8   __attribute__((ext_vector_type(8)));
typedef float    floatx4 __attribute__((ext_vector_type(4)));

// Hamilton product tables: out_comp = sum_c sign[comp][c] * (x_c @ W_{comp^c}^T)
__device__ __constant__ int   d_qtab[16] = {0,1,2,3,  1,0,3,2,  2,3,0,1,  3,2,1,0};
__device__ __constant__ float d_stab[16] = {1.f,-1.f,-1.f,-1.f,
                                            1.f, 1.f, 1.f,-1.f,
                                            1.f,-1.f, 1.f, 1.f,
                                            1.f, 1.f,-1.f, 1.f};

// ---------------- fused pre-pass: cast x -> fp16, cast W -> fp16 ----------------
__global__ void prepass_kernel(const float* __restrict__ x,
                               const float* __restrict__ W0, const float* __restrict__ W1,
                               const float* __restrict__ W2, const float* __restrict__ W3,
                               _Float16* __restrict__ xh, _Float16* __restrict__ Wh) {
    int b = blockIdx.x;
    if (b < 8192) {
        int idx = b * 256 + threadIdx.x;               // 0 .. 2M-1
        const float4* src = (const float4*)x + (size_t)idx * 2;
        float4 a = src[0], v = src[1];
        half8 h = {(_Float16)a.x, (_Float16)a.y, (_Float16)a.z, (_Float16)a.w,
                   (_Float16)v.x, (_Float16)v.y, (_Float16)v.z, (_Float16)v.w};
        ((half8*)xh)[idx] = h;
    } else {
        int idx = (b - 8192) * 256 + threadIdx.x;      // 0 .. 512K-1
        int e = idx << 3;                               // 0 .. 4M-1
        int m = e >> 20;
        int off = e & ((1 << 20) - 1);
        const float* Ws[4] = {W0, W1, W2, W3};
        const float* src = Ws[m] + off;
        float4 a = *(const float4*)src;
        float4 v = *(const float4*)(src + 4);
        half8 h = {(_Float16)a.x, (_Float16)a.y, (_Float16)a.z, (_Float16)a.w,
                   (_Float16)v.x, (_Float16)v.y, (_Float16)v.z, (_Float16)v.w};
        *(half8*)(Wh + ((size_t)m << 20) + off) = h;
    }
}

// --- MFMA GEMM: 256x256, BK=64, 8 waves; faithful m201 8-phase composition ---
// R7: B back in LDS (R6's direct-global B was 64-line scatter, request-bound).
// The one untested delta vs the proven 62%-MfmaUtil template is the PHASE
// COMPOSITION: m-major C-quadrants x full K=64, reads 12/4/8/4 per phase with
// register persistence (A-set lives 2 phases; B j01 re-read at ph4), lgkm(8)
// pacing hint in the 12-read phase, and a stage/vmcnt plan derived from
// quadrant free-times. Per K-tile tt (cur=tt&1, nxt=cur^1):
//  ph1 (m0 x j01): rd A-g0(8)+B j01(4); stage A-g1(t+1),B-h0(t+1),B-h1(t+1)->nxt
//  ph2 (m0 x j23): rd B j23(4)
//  ph3 (m1 x j23): rd A-g1(8); stage A-g0(t+2)->cur
//  ph4 (m1 x j01): rd B j01(4); WAITVM(2) after MFMA
// Each phase: reads; stages; [lgkm8]; BAR; lgkm0+schedbar; prio1; 16 MFMA;
// prio0; [vm]; BAR.
// vmcnt ledger (wave-uniform, FIFO): at ph4 outstanding = [prev-ph3 A-g0(t+1)
// (2), ph1 A-g1/B/B(t+1) (6), ph3 A-g0(t+2) (2)] = 10; WAITVM(2) retires all
// 8 of tile t+1 (read from next ph1, 1 barrier later). Prologue: tile0 full +
// A-g0(1), WAITVM(2). WAR: A-g0(cur) last ds-read ph1, overwritten ph3 (>=2
// BARs); A-g1/B(nxt) last read prev-tile ph3/ph4, overwritten ph1 (>=1 BAR).
// Tail: t1/t2 clamp to 63 (dead restage into freed regions, ledger invariant).
// Signs (R6-proven): accumulator flip at negseg boundaries + epilogue esign.
// LDS: rows of 64 halves (128B), slot = chunk ^ (row&7) (0 conflicts measured).

__device__ __forceinline__ void gload_lds16(const _Float16* g, _Float16* l) {
    __builtin_amdgcn_global_load_lds(
        (const __attribute__((address_space(1))) unsigned int*)g,
        (__attribute__((address_space(3))) unsigned int*)l,
        16, 0, 0);
}

#define BAR __builtin_amdgcn_s_barrier()
#define SCHEDB __builtin_amdgcn_sched_barrier(0)
#define WAITVM(N) asm volatile("s_waitcnt vmcnt(" #N ")" ::: "memory")
#define LGKM8 asm volatile("s_waitcnt lgkmcnt(8)" ::: "memory")
#define WAITLGKM0 do { asm volatile("s_waitcnt lgkmcnt(0)" ::: "memory"); \
                       SCHEDB; } while (0)

// stage A quadrant-half g of K-tile tt into buffer buf (rows {g*64..+63} u {128+g*64..+63})
#define STA(g, tt, buf) { \
    const _Float16* _s = Abase + (size_t)((g) * 64) * KDIM + (tt) * 64; \
    _Float16* _d = AsSt + (buf) * 16384 + (g) * 8192; \
    gload_lds16(_s, _d); \
    gload_lds16(_s + (size_t)128 * KDIM, _d + 4096); }

// stage B n-half h (cols h*128..h*128+127) of K-tile tt into buffer buf
#define STB(h, tt, buf) { \
    const int _sg = (tt) >> 4; \
    const _Float16* _s = Bbase + ((size_t)(comp ^ _sg) << 20) \
                       + (size_t)((h) * 128) * 1024 + ((tt) & 15) * 64; \
    _Float16* _d = BsSt + (buf) * 16384 + (h) * 8192; \
    gload_lds16(_s, _d); \
    gload_lds16(_s + 64 * 1024, _d + 4096); }

// read A-set: af[i][kh] for quadrant-half g (8 ds_read_b128)
#define RDA2(BASE, g) { \
    const _Float16* _p = (BASE) + (g) * 8192 + arow; \
    af[0][0] = *(const half8*)(_p + sl0);        af[0][1] = *(const half8*)(_p + sl1); \
    af[1][0] = *(const half8*)(_p + 1024 + sl0); af[1][1] = *(const half8*)(_p + 1024 + sl1); \
    af[2][0] = *(const half8*)(_p + 2048 + sl0); af[2][1] = *(const half8*)(_p + 2048 + sl1); \
    af[3][0] = *(const half8*)(_p + 3072 + sl0); af[3][1] = *(const half8*)(_p + 3072 + sl1); }

// read B-pair: bf[j][kh] for j-pair base jb (4 ds_read_b128)
#define RDB2(BASE, jb) { \
    const _Float16* _p = (BASE) + bnh * 8192 + brow + (jb) * 1024; \
    bf[0][0] = *(const half8*)(_p + sl0);        bf[0][1] = *(const half8*)(_p + sl1); \
    bf[1][0] = *(const half8*)(_p + 1024 + sl0); bf[1][1] = *(const half8*)(_p + 1024 + sl1); }

// one phase's 16 MFMA: quadrant (IB..IB+3) x (JB..JB+1), K=64 (kh0 then kh1)
#define MFMAPH(IB, JB) { \
    _Pragma("unroll") \
    for (int _i = 0; _i < 4; _i++) \
      _Pragma("unroll") \
      for (int _j = 0; _j < 2; _j++) \
        acc[(IB) + _i][(JB) + _j] = __builtin_amdgcn_mfma_f32_16x16x32_f16( \
            af[_i][0], bf[_j][0], acc[(IB) + _i][(JB) + _j], 0, 0, 0); \
    _Pragma("unroll") \
    for (int _i = 0; _i < 4; _i++) \
      _Pragma("unroll") \
      for (int _j = 0; _j < 2; _j++) \
        acc[(IB) + _i][(JB) + _j] = __builtin_amdgcn_mfma_f32_16x16x32_f16( \
            af[_i][1], bf[_j][1], acc[(IB) + _i][(JB) + _j], 0, 0, 0); }

__global__ __launch_bounds__(512, 2) void gemm_kernel(
        const _Float16* __restrict__ A,      // [4096,4096] fp16
        const _Float16* __restrict__ Wh,     // [4][1024][1024] fp16
        const float* __restrict__ b0, const float* __restrict__ b1,
        const float* __restrict__ b2, const float* __restrict__ b3,
        float* __restrict__ C) {
    __shared__ _Float16 lds[65536];          // 128 KiB
    _Float16* As = lds;                      // [buf][g][8192]
    _Float16* Bs = lds + 32768;              // [buf][h][8192]

    const int tid  = threadIdx.x;
    const int lane = tid & 63;
    const int wave = tid >> 6;               // 0..7
    const int wmh  = wave >> 2;              // M-half of 256-row tile (0/1)
    const int wn   = (wave & 3) * 64;        // N offset within 256-col tile
    const int bnh  = wn >> 7;                // which B region this wave reads
    const int broff = (wn & 64) * 64;        // 4K-block within B region

    // bijective XCD swizzle (nwg=256): each XCD gets 2 full bm-rows
    const int wg = ((blockIdx.x & 7) << 5) | (blockIdx.x >> 3);
    const int bm = wg >> 4, bn = wg & 15;
    const int m0 = bm << 8;
    const int n0 = bn << 8;
    const int comp = bn >> 2;                // output quaternion component
    const int n0q  = n0 & 1023;

    // staging geometry: 8 threads/row, 16B chunks, slot s holds chunk s^(row&7)
    const int lrow = tid >> 3;               // 0..63
    const int gch  = (tid & 7) ^ (lrow & 7);
    const _Float16* Abase = A  + (size_t)(m0  + lrow) * KDIM + gch * 8;
    const _Float16* Bbase = Wh + (size_t)(n0q + lrow) * 1024 + gch * 8;
    _Float16* AsSt = As + tid * 8;
    _Float16* BsSt = Bs + tid * 8;

    // fragment geometry (16x16x32): m/n = fr, k = kh*32 + qf*8 + j
    const int fr  = lane & 15;
    const int qf  = lane >> 4;
    const int fsw = fr & 7;
    const int sl0 = ((0 + qf) ^ fsw) * 8;    // kh=0 slot (halves)
    const int sl1 = ((4 + qf) ^ fsw) * 8;    // kh=1 slot
    const int arow = wmh * 4096 + fr * 64;   // within A quadrant region
    const int brow = broff + fr * 64;        // within B region

    // sign plan (R6-proven): negseg boundary acc-flips + epilogue esign
    const int negseg = (comp == 0) ? 0 : (comp == 1) ? 3 : (comp == 2) ? 1 : 2;
    const int negFlipA = (negseg == 0) ? 16 : negseg * 16;
    const int negFlipB = (negseg == 0 || negseg == 3) ? -1 : negseg * 16 + 16;
    const float esign = (comp <= 1) ? -1.f : 1.f;

    floatx4 acc[8][4];
#pragma unroll
    for (int i = 0; i < 8; i++)
#pragma unroll
        for (int j = 0; j < 4; j++)
            acc[i][j] = (floatx4){0.f, 0.f, 0.f, 0.f};

    half8 af[4][2], bf[2][2];

    // ---- prologue: tile0 fully + A-g0(1); WAITVM(2) leaves A-g0(1) in flight
    STA(0, 0, 0); STA(1, 0, 0);
    STB(0, 0, 0); STB(1, 0, 0);
    STA(0, 1, 1);
    WAITVM(2);
    BAR;

    for (int tt = 0; tt < 64; ++tt) {
        const int cur = tt & 1, nxt = cur ^ 1;
        const _Float16* Acur = As + cur * 16384;
        const _Float16* Bcur = Bs + cur * 16384;
        const int t1 = (tt >= 63) ? 63 : tt + 1;
        const int t2 = (tt >= 62) ? 63 : tt + 2;

        // segment-boundary accumulator flip (<=2 per kernel, wave-uniform)
        if (tt == negFlipA || tt == negFlipB) {
#pragma unroll
            for (int i = 0; i < 8; i++)
#pragma unroll
                for (int j = 0; j < 4; j++)
                    acc[i][j] = -acc[i][j];
        }

        // ---- ph1 (m0 x j01): 12 reads; stage A-g1(t1),B-h0(t1),B-h1(t1)->nxt
        RDA2(Acur, 0);
        RDB2(Bcur, 0);
        STA(1, t1, nxt);
        STB(0, t1, nxt);
        STB(1, t1, nxt);
        LGKM8;
        BAR; WAITLGKM0;
        __builtin_amdgcn_s_setprio(1);
        MFMAPH(0, 0);
        __builtin_amdgcn_s_setprio(0);
        BAR;

        // ---- ph2 (m0 x j23): 4 reads (A-set persists)
        RDB2(Bcur, 2);
        BAR; WAITLGKM0;
        __builtin_amdgcn_s_setprio(1);
        MFMAPH(0, 2);
        __builtin_amdgcn_s_setprio(0);
        BAR;

        // ---- ph3 (m1 x j23): 8 reads (B j23 persists); stage A-g0(t2)->cur
        RDA2(Acur, 1);
        STA(0, t2, cur);                     // region's last ds-read was ph1
        BAR; WAITLGKM0;
        __builtin_amdgcn_s_setprio(1);
        MFMAPH(4, 2);
        __builtin_amdgcn_s_setprio(0);
        BAR;

        // ---- ph4 (m1 x j01): 4 reads (B j01 re-read); counted vmcnt
        RDB2(Bcur, 0);
        BAR; WAITLGKM0;
        __builtin_amdgcn_s_setprio(1);
        MFMAPH(4, 0);
        __builtin_amdgcn_s_setprio(0);
        WAITVM(2);                           // retires all of tile t+1's 8 DMAs
        BAR;
    }

    WAITVM(0);   // drain tail DMAs before LDS teardown

    // Epilogue: D[row][col], col = lane&15, row = (lane>>4)*4 + r  [m89 layout]
    const int col   = lane & 15;
    const int rquad = (lane >> 4) * 4;
    const int wm    = wmh * 128;
    const float* bsp[4] = {b0, b1, b2, b3};
#pragma unroll
    for (int j = 0; j < 4; j++) {
        const int gn = n0 + wn + j * 16 + col;
        const int o  = gn & 1023;
        float bv = 0.f;
#pragma unroll
        for (int c = 0; c < 4; c++)
            bv += d_stab[comp * 4 + c] * bsp[comp ^ c][o];
#pragma unroll
        for (int i = 0; i < 8; i++) {
            const int gmb = m0 + wm + i * 16 + rquad;
#pragma unroll
            for (int r = 0; r < 4; r++)
                C[(size_t)(gmb + r) * NDIM + gn] = esign * acc[i][j][r] + bv;
        }
    }
}

// ---------------- fp32 fallback (only if ws too small) ----------------
__global__ void fallback_kernel(const float* __restrict__ x,
                                const float* __restrict__ W0, const float* __restrict__ W1,
                                const float* __restrict__ W2, const float* __restrict__ W3,
                                const float* __restrict__ b0, const float* __restrict__ b1,
                                const float* __restrict__ b2, const float* __restrict__ b3,
                                float* __restrict__ out) {
    int idx = blockIdx.x * 256 + threadIdx.x;   // 16M outputs
    int m = idx >> 12, n = idx & 4095;
    int comp = n >> 10, o = n & 1023;
    const float* Ws[4] = {W0, W1, W2, W3};
    const float* bs[4] = {b0, b1, b2, b3};
    float acc = 0.f;
    for (int c = 0; c < 4; c++) {
        int t = comp * 4 + c;
        const float* wr = Ws[d_qtab[t]] + (size_t)o * 1024;
        const float* xr = x + (size_t)m * 4096 + c * 1024;
        float s = d_stab[t];
        float dot = 0.f;
        for (int i = 0; i < 1024; i += 4) {
            float4 wv = *(const float4*)(wr + i);
            float4 xv = *(const float4*)(xr + i);
            dot += wv.x * xv.x + wv.y * xv.y + wv.z * xv.z + wv.w * xv.w;
        }
        acc += s * dot + s * bs[d_qtab[t]][o];
    }
    out[idx] = acc;
}

// ---------------- launch ----------------
extern "C" void kernel_launch(void* const* d_in, const int* in_sizes, int n_in,
                              void* d_out, int out_size, void* d_ws, size_t ws_size,
                              hipStream_t stream) {
    const float* x = (const float*)d_in[0];
    const float* W[4];
    const float* b[4];
    int wi = 0, bi = 0;
    for (int i = 1; i < n_in && i < 9; i++) {
        if (in_sizes[i] > 4096) { if (wi < 4) W[wi++] = (const float*)d_in[i]; }
        else                    { if (bi < 4) b[bi++] = (const float*)d_in[i]; }
    }
    float* out = (float*)d_out;

    const size_t xh_elems = (size_t)MDIM * KDIM;        // 16M fp16 = 32 MB
    const size_t wh_elems = (size_t)4 * 1024 * 1024;    // 4M fp16 = 8 MB
    const size_t needed = (xh_elems + wh_elems) * 2;

    if (ws_size < needed) {
        fallback_kernel<<<(MDIM * NDIM) / 256, 256, 0, stream>>>(
            x, W[0], W[1], W[2], W[3], b[0], b[1], b[2], b[3], out);
        return;
    }

    _Float16* xh = (_Float16*)d_ws;
    _Float16* Wh = xh + xh_elems;

    prepass_kernel<<<8192 + 2048, 256, 0, stream>>>(x, W[0], W[1], W[2], W[3], xh, Wh);
    gemm_kernel<<<(MDIM / 256) * (NDIM / 256), 512, 0, stream>>>(
        xh, Wh, b[0], b[1], b[2], b[3], out);
}